// Round 8
// baseline (2138.942 us; speedup 1.0000x reference)
//
#include <hip/hip_runtime.h>
#include <hip/hip_bf16.h>

#define NNODES 100000
#define NEDGES 1600000
#define IND 128
#define HD 64
#define OUTD 2
#define NG 64
#define BINSHIFT 6
#define BINSZ 64             // dst nodes per bin (16 KB fp32 LDS accumulator)
#define MAXBINS 1600
#define PB 256               // partition blocks

typedef __attribute__((ext_vector_type(8))) short short8v;
typedef __attribute__((ext_vector_type(4))) float floatx4;

static __device__ __forceinline__ unsigned short f2bf(float f) {
    __hip_bfloat16 h = __float2bfloat16(f);
    return *(unsigned short*)&h;
}
static __device__ __forceinline__ float bf2f(unsigned short u) {
    __hip_bfloat16 h = *(__hip_bfloat16*)&u;
    return __bfloat162float(h);
}

// ============ binned edge partition ============
// A: per-block bin histogram (LDS), no global atomics.
__global__ __launch_bounds__(256) void binA_kernel(const int* __restrict__ dst,
                                                   int* __restrict__ bbc,
                                                   int E, int nbins) {
    __shared__ int lh[MAXBINS];
    for (int i = threadIdx.x; i < nbins; i += 256) lh[i] = 0;
    __syncthreads();
    int ebpb = (E + PB - 1) / PB;
    int e0 = blockIdx.x * ebpb;
    int e1 = min(e0 + ebpb, E);
    for (int e = e0 + threadIdx.x; e < e1; e += 256)
        atomicAdd(&lh[dst[e] >> BINSHIFT], 1);
    __syncthreads();
    for (int i = threadIdx.x; i < nbins; i += 256)
        bbc[blockIdx.x * nbins + i] = lh[i];
}

// B1: per-bin exclusive scan across the PB partition blocks.
__global__ __launch_bounds__(256) void binB1_kernel(int* __restrict__ bbc,
                                                    int* __restrict__ binTotal,
                                                    int* __restrict__ binStart,
                                                    int nbins) {
    __shared__ int ws[4];
    int b = blockIdx.x;
    int t = threadIdx.x, lane = t & 63, wv = t >> 6;
    int v = bbc[t * nbins + b];
    int sc = v;
#pragma unroll
    for (int d = 1; d < 64; d <<= 1) { int u = __shfl_up(sc, d, 64); if (lane >= d) sc += u; }
    if (lane == 63) ws[wv] = sc;
    __syncthreads();
    int add = 0;
    for (int w = 0; w < wv; w++) add += ws[w];
    bbc[t * nbins + b] = sc - v + add;
    if (t == 255) { int tot = sc + add; binTotal[b] = tot; binStart[b] = tot; }
}

// 1-wave exclusive scan over nbins (<= 2048) values in place.
__global__ __launch_bounds__(64) void scan_bsums_kernel(int* __restrict__ bsum, int nchunks) {
    int lane = threadIdx.x;
    int cpl = (nchunks + 63) / 64;     // <= 32
    int vals[32];
    int i0 = lane * cpl;
    int t = 0;
    for (int k = 0; k < cpl; k++) {
        int i = i0 + k;
        vals[k] = (i < nchunks) ? bsum[i] : 0;
        t += vals[k];
    }
    int sc = t;
#pragma unroll
    for (int d = 1; d < 64; d <<= 1) { int v = __shfl_up(sc, d, 64); if (lane >= d) sc += v; }
    int ex = sc - t;
    for (int k = 0; k < cpl; k++) {
        int i = i0 + k;
        if (i < nchunks) bsum[i] = ex;
        ex += vals[k];
    }
}

// C: partition edges into bin-contiguous packed records.
// record = (doff << 17) | src   (src < 2^17, doff < 2^6)
__global__ __launch_bounds__(256) void binC_kernel(const int* __restrict__ src,
                                                   const int* __restrict__ dst,
                                                   const int* __restrict__ bbc,
                                                   const int* __restrict__ binStart,
                                                   unsigned int* __restrict__ binned,
                                                   int E, int nbins) {
    __shared__ int cur[MAXBINS];
    int t = threadIdx.x;
    for (int i = t; i < nbins; i += 256)
        cur[i] = binStart[i] + bbc[blockIdx.x * nbins + i];
    __syncthreads();
    int ebpb = (E + PB - 1) / PB;
    int e0 = blockIdx.x * ebpb;
    int e1 = min(e0 + ebpb, E);
    for (int e = e0 + t; e < e1; e += 256) {
        int d = dst[e];
        int b = d >> BINSHIFT;
        int p = atomicAdd(&cur[b], 1);
        binned[p] = ((unsigned int)(d & (BINSZ - 1)) << 17) | (unsigned int)src[e];
    }
}

// H: per-bin node degree histogram (LDS) -> dinv only (no CSR needed anymore).
__global__ __launch_bounds__(256) void binH_kernel(const unsigned int* __restrict__ binned,
                                                   const int* __restrict__ binStart,
                                                   const int* __restrict__ binTotal,
                                                   float* __restrict__ dinv, int n) {
    __shared__ int dh[BINSZ];
    int b = blockIdx.x;
    int t = threadIdx.x;
    if (t < BINSZ) dh[t] = 0;
    __syncthreads();
    int s0 = binStart[b], cnt = binTotal[b];
    for (int i = t; i < cnt; i += 256)
        atomicAdd(&dh[binned[s0 + i] >> 17], 1);
    __syncthreads();
    if (t < BINSZ) {
        int node = (b << BINSHIFT) + t;
        if (node < n) dinv[node] = 1.0f / sqrtf((float)(dh[t] + 1));
    }
}

// ---------------- W transpose + bf16 convert: WT[n][k] = bf16(W[k][n]) -----
__global__ __launch_bounds__(256) void cvtWT_kernel(const float* __restrict__ W,
                                                    unsigned short* __restrict__ WT, int K) {
    int i = blockIdx.x * 256 + threadIdx.x;
    if (i < 64 * K) {
        int n = i / K, k = i - n * K;
        WT[i] = f2bf(W[k * 64 + n]);
    }
}

// ---------------- MFMA matmul: Tb[n][:] = bf16( dinv[n] * (X[n,:K] @ W) ) --
template <int K, bool BF16IN>
__global__ __launch_bounds__(256) void mm_mfma_kernel(const void* __restrict__ Xv,
                                                      const unsigned short* __restrict__ WT,
                                                      const float* __restrict__ dinv,
                                                      unsigned short* __restrict__ Tb, int nn) {
    const int lane = threadIdx.x & 63;
    const int wv   = threadIdx.x >> 6;
    const int nb   = blockIdx.x * 64 + wv * 16;
    if (nb >= nn) return;
    const int col  = lane & 15;
    const int quad = lane >> 4;
    const int m    = min(nb + col, nn - 1);

    floatx4 acc0 = {0.f, 0.f, 0.f, 0.f};
    floatx4 acc1 = {0.f, 0.f, 0.f, 0.f};
    floatx4 acc2 = {0.f, 0.f, 0.f, 0.f};
    floatx4 acc3 = {0.f, 0.f, 0.f, 0.f};

#pragma unroll
    for (int ks = 0; ks < K; ks += 32) {
        const int k0 = ks + quad * 8;
        short8v a;
        if (BF16IN) {
            a = *(const short8v*)((const unsigned short*)Xv + (size_t)m * K + k0);
        } else {
            const float* xr = (const float*)Xv + (size_t)m * K + k0;
            float4 f0 = *(const float4*)(xr);
            float4 f1 = *(const float4*)(xr + 4);
            a[0] = (short)f2bf(f0.x); a[1] = (short)f2bf(f0.y);
            a[2] = (short)f2bf(f0.z); a[3] = (short)f2bf(f0.w);
            a[4] = (short)f2bf(f1.x); a[5] = (short)f2bf(f1.y);
            a[6] = (short)f2bf(f1.z); a[7] = (short)f2bf(f1.w);
        }
        short8v b0 = *(const short8v*)(WT + (size_t)(0  + col) * K + k0);
        short8v b1 = *(const short8v*)(WT + (size_t)(16 + col) * K + k0);
        short8v b2 = *(const short8v*)(WT + (size_t)(32 + col) * K + k0);
        short8v b3 = *(const short8v*)(WT + (size_t)(48 + col) * K + k0);
        acc0 = __builtin_amdgcn_mfma_f32_16x16x32_bf16(a, b0, acc0, 0, 0, 0);
        acc1 = __builtin_amdgcn_mfma_f32_16x16x32_bf16(a, b1, acc1, 0, 0, 0);
        acc2 = __builtin_amdgcn_mfma_f32_16x16x32_bf16(a, b2, acc2, 0, 0, 0);
        acc3 = __builtin_amdgcn_mfma_f32_16x16x32_bf16(a, b3, acc3, 0, 0, 0);
    }

#pragma unroll
    for (int r = 0; r < 4; r++) {
        int node = nb + quad * 4 + r;
        if (node < nn) {
            float sc = dinv[node];
            unsigned short* o = Tb + (size_t)node * 64 + col;
            o[0]  = f2bf(sc * acc0[r]);
            o[16] = f2bf(sc * acc1[r]);
            o[32] = f2bf(sc * acc2[r]);
            o[48] = f2bf(sc * acc3[r]);
        }
    }
}

// ---------------- edge-centric aggregation into LDS bin accumulators -------
// Block = one bin of 64 dst nodes; fp32 accumulator in LDS (16 KB).
// Wave loads 64 edge records into lanes, then 64 broadcast iterations:
// src is wave-uniform -> one coalesced 128 B row gather; ds_add_f32 lane=feat
// (conflict-free, no-return -> fire-and-forget). Continuous gather stream,
// no per-node pipeline drain. Epilogue: + self row, * dinv, + bias, relu.
__global__ __launch_bounds__(256) void aggbin_kernel(const unsigned short* __restrict__ Tb,
                                                     const unsigned int* __restrict__ binned,
                                                     const int* __restrict__ binStart,
                                                     const int* __restrict__ binTotal,
                                                     const float* __restrict__ dinv,
                                                     const float* __restrict__ bias,
                                                     unsigned short* __restrict__ Ob, int nn) {
    __shared__ float acc[BINSZ * 64];
    int b = blockIdx.x;
    int t = threadIdx.x;
    int lane = t & 63, wv = t >> 6;
    for (int i = t; i < BINSZ * 64; i += 256) acc[i] = 0.f;
    __syncthreads();
    int s0 = binStart[b], cnt = binTotal[b];
    for (int base = wv * 64; base < cnt; base += 4 * 64) {
        int myi = base + lane;
        unsigned int rec = (myi < cnt) ? binned[s0 + myi] : 0u;
        int m = cnt - base; if (m > 64) m = 64;
        if (m == 64) {
#pragma unroll 8
            for (int k = 0; k < 64; k++) {
                unsigned int r = __shfl(rec, k, 64);
                int s = r & 0x1FFFF;
                int doff = r >> 17;
                float v = bf2f(Tb[(size_t)s * 64 + lane]);
                atomicAdd(&acc[doff * 64 + lane], v);
            }
        } else {
            for (int k = 0; k < m; k++) {
                unsigned int r = __shfl(rec, k, 64);
                int s = r & 0x1FFFF;
                int doff = r >> 17;
                float v = bf2f(Tb[(size_t)s * 64 + lane]);
                atomicAdd(&acc[doff * 64 + lane], v);
            }
        }
    }
    __syncthreads();
    // epilogue: wave wv handles nodes wv, wv+4, ... within the bin
    for (int i = wv; i < BINSZ; i += 4) {
        int node = (b << BINSHIFT) + i;
        if (node < nn) {
            float a = acc[i * 64 + lane] + bf2f(Tb[(size_t)node * 64 + lane]);
            float o = dinv[node] * a + bias[lane];
            o = o > 0.f ? o : 0.f;
            Ob[(size_t)node * 64 + lane] = f2bf(o);
        }
    }
}

// ---------------- mean pool (bf16 input): exploit sorted batch ids ---------
__global__ __launch_bounds__(256) void pool_kernel(const unsigned short* __restrict__ Hb,
                                                   const int* __restrict__ batch,
                                                   float* __restrict__ pooled,
                                                   float* __restrict__ gcnt, int nn) {
    int wid = (blockIdx.x * 256 + threadIdx.x) >> 6;
    int lane = threadIdx.x & 63;
    int nwaves = (gridDim.x * 256) >> 6;
    int per = (nn + nwaves - 1) / nwaves;
    int n0 = wid * per;
    int n1 = n0 + per; if (n1 > nn) n1 = nn;
    if (n0 >= n1) return;
    int cur = batch[n0];
    float acc = 0.f, cnt = 0.f;
    for (int n = n0; n < n1; ++n) {
        int g = batch[n];
        if (g != cur) {
            atomicAdd(&pooled[cur * 64 + lane], acc);
            if (lane == 0) atomicAdd(&gcnt[cur], cnt);
            acc = 0.f; cnt = 0.f; cur = g;
        }
        acc += bf2f(Hb[(size_t)n * 64 + lane]);
        cnt += 1.f;
    }
    atomicAdd(&pooled[cur * 64 + lane], acc);
    if (lane == 0) atomicAdd(&gcnt[cur], cnt);
}

// ---------------- MLP head (single block) ----------------
__global__ __launch_bounds__(256) void head_kernel(const float* __restrict__ pooled,
                                                   const float* __restrict__ gcnt,
                                                   const float* __restrict__ Wm1,
                                                   const float* __restrict__ bm1,
                                                   const float* __restrict__ Wm2,
                                                   const float* __restrict__ bm2,
                                                   float* __restrict__ out) {
    __shared__ float P[NG * 64];
    __shared__ float Z[NG * 64];
    int tid = threadIdx.x;
    for (int i = tid; i < NG * 64; i += 256) {
        int g = i >> 6;
        float c = gcnt[g];
        c = c > 1.f ? c : 1.f;
        P[i] = pooled[i] / c;
    }
    __syncthreads();
    for (int i = tid; i < NG * 64; i += 256) {
        int g = i >> 6, j = i & 63;
        float a = bm1[j];
#pragma unroll 8
        for (int k = 0; k < 64; ++k) a += P[g * 64 + k] * Wm1[k * 64 + j];
        Z[i] = a > 0.f ? a : 0.f;
    }
    __syncthreads();
    for (int i = tid; i < NG * OUTD; i += 256) {
        int g = i / OUTD, o = i % OUTD;
        float a = bm2[o];
#pragma unroll 8
        for (int k = 0; k < 64; ++k) a += Z[g * 64 + k] * Wm2[k * OUTD + o];
        out[i] = a;
    }
}

extern "C" void kernel_launch(void* const* d_in, const int* in_sizes, int n_in,
                              void* d_out, int out_size, void* d_ws, size_t ws_size,
                              hipStream_t stream) {
    const float* x    = (const float*)d_in[0];
    const int*  edge  = (const int*)d_in[1];
    const int*  batch = (const int*)d_in[2];
    const float* W1 = (const float*)d_in[3];
    const float* b1 = (const float*)d_in[4];
    const float* W2 = (const float*)d_in[5];
    const float* b2 = (const float*)d_in[6];
    const float* W3 = (const float*)d_in[7];
    const float* b3 = (const float*)d_in[8];
    const float* Wm1 = (const float*)d_in[9];
    const float* bm1 = (const float*)d_in[10];
    const float* Wm2 = (const float*)d_in[11];
    const float* bm2 = (const float*)d_in[12];

    const int N_ = in_sizes[2];           // 100000
    const int E_ = in_sizes[1] / 2;       // 1600000
    const int* src = edge;
    const int* dst = edge + E_;
    const int nbins = (N_ + BINSZ - 1) >> BINSHIFT;   // 1563

    // workspace carve (256 B aligned)
    char* w = (char*)d_ws;
    auto alloc = [&](size_t bytes) -> void* {
        void* p = (void*)w;
        w += (bytes + 255) & ~(size_t)255;
        return p;
    };
    float* dinv     = (float*)alloc((size_t)N_ * 4);
    int*   bbc      = (int*)alloc((size_t)PB * nbins * 4);
    int*   binTotal = (int*)alloc((size_t)MAXBINS * 4);
    int*   binStart = (int*)alloc((size_t)MAXBINS * 4);
    unsigned int* binned = (unsigned int*)alloc((size_t)E_ * 4);
    unsigned short* Tb  = (unsigned short*)alloc((size_t)N_ * 64 * 2);
    unsigned short* hBb = (unsigned short*)alloc((size_t)N_ * 64 * 2);
    unsigned short* WT1 = (unsigned short*)alloc((size_t)64 * IND * 2);
    unsigned short* WT2 = (unsigned short*)alloc((size_t)64 * HD * 2);
    unsigned short* WT3 = (unsigned short*)alloc((size_t)64 * HD * 2);
    float* pooled = (float*)alloc((size_t)(NG * 64 + NG) * 4);
    float* gcnt   = pooled + NG * 64;

    hipMemsetAsync(pooled, 0, (size_t)(NG * 64 + NG) * 4, stream);

    // ---- binned edge partition (no CSR, no rowptr) ----
    binA_kernel<<<PB, 256, 0, stream>>>(dst, bbc, E_, nbins);
    binB1_kernel<<<nbins, 256, 0, stream>>>(bbc, binTotal, binStart, nbins);
    scan_bsums_kernel<<<1, 64, 0, stream>>>(binStart, nbins);
    binC_kernel<<<PB, 256, 0, stream>>>(src, dst, bbc, binStart, binned, E_, nbins);
    binH_kernel<<<nbins, 256, 0, stream>>>(binned, binStart, binTotal, dinv, N_);

    // ---- weight transposes (tiny) ----
    cvtWT_kernel<<<(64 * IND + 255) / 256, 256, 0, stream>>>(W1, WT1, IND);
    cvtWT_kernel<<<(64 * HD + 255) / 256, 256, 0, stream>>>(W2, WT2, HD);
    cvtWT_kernel<<<(64 * HD + 255) / 256, 256, 0, stream>>>(W3, WT3, HD);

    const int mmblk = (N_ + 63) / 64;             // 64 nodes per block (4 waves x 16)

    // layer 1
    mm_mfma_kernel<IND, false><<<mmblk, 256, 0, stream>>>(x, WT1, dinv, Tb, N_);
    aggbin_kernel<<<nbins, 256, 0, stream>>>(Tb, binned, binStart, binTotal, dinv, b1, hBb, N_);
    // layer 2
    mm_mfma_kernel<HD, true><<<mmblk, 256, 0, stream>>>(hBb, WT2, dinv, Tb, N_);
    aggbin_kernel<<<nbins, 256, 0, stream>>>(Tb, binned, binStart, binTotal, dinv, b2, hBb, N_);
    // layer 3
    mm_mfma_kernel<HD, true><<<mmblk, 256, 0, stream>>>(hBb, WT3, dinv, Tb, N_);
    aggbin_kernel<<<nbins, 256, 0, stream>>>(Tb, binned, binStart, binTotal, dinv, b3, hBb, N_);

    // pool + head
    pool_kernel<<<256, 256, 0, stream>>>(hBb, batch, pooled, gcnt, N_);
    head_kernel<<<1, 256, 0, stream>>>(pooled, gcnt, Wm1, bm1, Wm2, bm2, (float*)d_out);
}

// Round 9
// 411.018 us; speedup vs baseline: 5.2040x; 5.2040x over previous
//
#include <hip/hip_runtime.h>
#include <hip/hip_bf16.h>

#define NNODES 100000
#define NEDGES 1600000
#define IND 128
#define HD 64
#define OUTD 2
#define NG 64
#define SCAN_CHUNK 1024
#define BINSHIFT 9
#define BINSZ 512            // nodes per bin
#define PB 256               // partition blocks

typedef __attribute__((ext_vector_type(8))) short short8v;
typedef __attribute__((ext_vector_type(4))) float floatx4;

static __device__ __forceinline__ unsigned short f2bf(float f) {
    __hip_bfloat16 h = __float2bfloat16(f);
    return *(unsigned short*)&h;
}
static __device__ __forceinline__ float bf2f(unsigned short u) {
    __hip_bfloat16 h = *(__hip_bfloat16*)&u;
    return __bfloat162float(h);
}

// ============ binned CSR build (round-7 proven) ============
__global__ __launch_bounds__(256) void binA_kernel(const int* __restrict__ dst,
                                                   int* __restrict__ bbc,
                                                   int E, int nbins) {
    __shared__ int lh[256];
    lh[threadIdx.x] = 0;
    __syncthreads();
    int ebpb = (E + PB - 1) / PB;
    int e0 = blockIdx.x * ebpb;
    int e1 = min(e0 + ebpb, E);
    for (int e = e0 + threadIdx.x; e < e1; e += 256)
        atomicAdd(&lh[dst[e] >> BINSHIFT], 1);
    __syncthreads();
    bbc[blockIdx.x * 256 + threadIdx.x] = lh[threadIdx.x];
}

__global__ __launch_bounds__(256) void binB1_kernel(int* __restrict__ bbc,
                                                    int* __restrict__ binTotal,
                                                    int* __restrict__ binStart) {
    __shared__ int ws[4];
    int b = blockIdx.x;
    int t = threadIdx.x, lane = t & 63, wv = t >> 6;
    int v = bbc[t * 256 + b];
    int sc = v;
#pragma unroll
    for (int d = 1; d < 64; d <<= 1) { int u = __shfl_up(sc, d, 64); if (lane >= d) sc += u; }
    if (lane == 63) ws[wv] = sc;
    __syncthreads();
    int add = 0;
    for (int w = 0; w < wv; w++) add += ws[w];
    bbc[t * 256 + b] = sc - v + add;
    if (t == 255) { int tot = sc + add; binTotal[b] = tot; binStart[b] = tot; }
}

__global__ __launch_bounds__(64) void scan_bsums_kernel(int* __restrict__ bsum, int nchunks) {
    int lane = threadIdx.x;
    int cpl = (nchunks + 63) / 64;     // <= 8 assumed
    int vals[8];
    int i0 = lane * cpl;
    int t = 0;
    for (int k = 0; k < cpl; k++) {
        int i = i0 + k;
        vals[k] = (i < nchunks) ? bsum[i] : 0;
        t += vals[k];
    }
    int sc = t;
#pragma unroll
    for (int d = 1; d < 64; d <<= 1) { int v = __shfl_up(sc, d, 64); if (lane >= d) sc += v; }
    int ex = sc - t;
    for (int k = 0; k < cpl; k++) {
        int i = i0 + k;
        if (i < nchunks) bsum[i] = ex;
        ex += vals[k];
    }
}

// record = (doff << 17) | src   (src < 2^17, doff < 2^9)
__global__ __launch_bounds__(256) void binC_kernel(const int* __restrict__ src,
                                                   const int* __restrict__ dst,
                                                   const int* __restrict__ bbc,
                                                   const int* __restrict__ binStart,
                                                   unsigned int* __restrict__ binned,
                                                   int E, int nbins) {
    __shared__ int cur[256];
    int t = threadIdx.x;
    if (t < nbins) cur[t] = binStart[t] + bbc[blockIdx.x * 256 + t];
    __syncthreads();
    int ebpb = (E + PB - 1) / PB;
    int e0 = blockIdx.x * ebpb;
    int e1 = min(e0 + ebpb, E);
    for (int e = e0 + t; e < e1; e += 256) {
        int d = dst[e];
        int b = d >> BINSHIFT;
        int p = atomicAdd(&cur[b], 1);
        binned[p] = ((unsigned int)(d & (BINSZ - 1)) << 17) | (unsigned int)src[e];
    }
}

__global__ __launch_bounds__(256) void binH_kernel(const unsigned int* __restrict__ binned,
                                                   const int* __restrict__ binStart,
                                                   const int* __restrict__ binTotal,
                                                   int* __restrict__ hist,
                                                   float* __restrict__ dinv, int n) {
    __shared__ int dh[BINSZ];
    int b = blockIdx.x;
    int t = threadIdx.x;
    dh[t] = 0; dh[t + 256] = 0;
    __syncthreads();
    int s0 = binStart[b], cnt = binTotal[b];
    for (int i = t; i < cnt; i += 256)
        atomicAdd(&dh[binned[s0 + i] >> 17], 1);
    __syncthreads();
#pragma unroll
    for (int r = 0; r < 2; r++) {
        int i = t + r * 256;
        int node = (b << BINSHIFT) + i;
        if (node < n) {
            int dg = dh[i];
            hist[node] = dg;
            dinv[node] = 1.0f / sqrtf((float)(dg + 1));
        }
    }
}

__global__ __launch_bounds__(256) void scan_sum_kernel(const int* __restrict__ hist,
                                                       int* __restrict__ bsum, int n) {
    __shared__ int wsums[4];
    int lane = threadIdx.x & 63, wv = threadIdx.x >> 6;
    int i0 = blockIdx.x * SCAN_CHUNK + threadIdx.x * 4;
    int t = 0;
#pragma unroll
    for (int k = 0; k < 4; k++) { int i = i0 + k; if (i < n) t += hist[i]; }
#pragma unroll
    for (int d = 32; d > 0; d >>= 1) t += __shfl_down(t, d, 64);
    if (lane == 0) wsums[wv] = t;
    __syncthreads();
    if (threadIdx.x == 0) bsum[blockIdx.x] = wsums[0] + wsums[1] + wsums[2] + wsums[3];
}

__global__ __launch_bounds__(256) void scan_write_kernel(const int* __restrict__ hist,
                                                         const int* __restrict__ bofs,
                                                         int* __restrict__ rowptr,
                                                         int n, int total) {
    __shared__ int wsum[4];
    int lane = threadIdx.x & 63, wv = threadIdx.x >> 6;
    int i0 = blockIdx.x * SCAN_CHUNK + threadIdx.x * 4;
    int h[4]; int t = 0;
#pragma unroll
    for (int k = 0; k < 4; k++) { int i = i0 + k; h[k] = (i < n) ? hist[i] : 0; t += h[k]; }
    int sc = t;
#pragma unroll
    for (int d = 1; d < 64; d <<= 1) { int v = __shfl_up(sc, d, 64); if (lane >= d) sc += v; }
    if (lane == 63) wsum[wv] = sc;
    __syncthreads();
    int wofs = 0;
    for (int w = 0; w < wv; w++) wofs += wsum[w];
    int ex = (sc - t) + wofs + bofs[blockIdx.x];
#pragma unroll
    for (int k = 0; k < 4; k++) { int i = i0 + k; if (i < n) rowptr[i] = ex; ex += h[k]; }
    if (blockIdx.x == 0 && threadIdx.x == 0) rowptr[n] = total;
}

__global__ __launch_bounds__(256) void binD_kernel(const unsigned int* __restrict__ binned,
                                                   const int* __restrict__ binStart,
                                                   const int* __restrict__ binTotal,
                                                   const int* __restrict__ hist,
                                                   const int* __restrict__ rowptr,
                                                   int* __restrict__ ssrc, int n) {
    __shared__ int cntL[BINSZ];
    __shared__ int rpL[BINSZ];
    int b = blockIdx.x;
    int t = threadIdx.x;
#pragma unroll
    for (int r = 0; r < 2; r++) {
        int i = t + r * 256;
        int node = (b << BINSHIFT) + i;
        if (node < n) { cntL[i] = hist[node]; rpL[i] = rowptr[node]; }
    }
    __syncthreads();
    int s0 = binStart[b], cnt = binTotal[b];
    for (int i = t; i < cnt; i += 256) {
        unsigned int rec = binned[s0 + i];
        int doff = rec >> 17;
        int s = rec & 0x1FFFF;
        int idx = atomicSub(&cntL[doff], 1) - 1;
        ssrc[rpL[doff] + idx] = s;
    }
}

// ---------------- W transpose + bf16 convert: WT[n][k] = bf16(W[k][n]) -----
__global__ __launch_bounds__(256) void cvtWT_kernel(const float* __restrict__ W,
                                                    unsigned short* __restrict__ WT, int K) {
    int i = blockIdx.x * 256 + threadIdx.x;
    if (i < 64 * K) {
        int n = i / K, k = i - n * K;
        WT[i] = f2bf(W[k * 64 + n]);
    }
}

// ---------------- MFMA matmul: Tb[n][:] = bf16( dinv[n] * (X[n,:K] @ W) ) --
template <int K, bool BF16IN>
__global__ __launch_bounds__(256) void mm_mfma_kernel(const void* __restrict__ Xv,
                                                      const unsigned short* __restrict__ WT,
                                                      const float* __restrict__ dinv,
                                                      unsigned short* __restrict__ Tb, int nn) {
    const int lane = threadIdx.x & 63;
    const int wv   = threadIdx.x >> 6;
    const int nb   = blockIdx.x * 64 + wv * 16;
    if (nb >= nn) return;
    const int col  = lane & 15;
    const int quad = lane >> 4;
    const int m    = min(nb + col, nn - 1);

    floatx4 acc0 = {0.f, 0.f, 0.f, 0.f};
    floatx4 acc1 = {0.f, 0.f, 0.f, 0.f};
    floatx4 acc2 = {0.f, 0.f, 0.f, 0.f};
    floatx4 acc3 = {0.f, 0.f, 0.f, 0.f};

#pragma unroll
    for (int ks = 0; ks < K; ks += 32) {
        const int k0 = ks + quad * 8;
        short8v a;
        if (BF16IN) {
            a = *(const short8v*)((const unsigned short*)Xv + (size_t)m * K + k0);
        } else {
            const float* xr = (const float*)Xv + (size_t)m * K + k0;
            float4 f0 = *(const float4*)(xr);
            float4 f1 = *(const float4*)(xr + 4);
            a[0] = (short)f2bf(f0.x); a[1] = (short)f2bf(f0.y);
            a[2] = (short)f2bf(f0.z); a[3] = (short)f2bf(f0.w);
            a[4] = (short)f2bf(f1.x); a[5] = (short)f2bf(f1.y);
            a[6] = (short)f2bf(f1.z); a[7] = (short)f2bf(f1.w);
        }
        short8v b0 = *(const short8v*)(WT + (size_t)(0  + col) * K + k0);
        short8v b1 = *(const short8v*)(WT + (size_t)(16 + col) * K + k0);
        short8v b2 = *(const short8v*)(WT + (size_t)(32 + col) * K + k0);
        short8v b3 = *(const short8v*)(WT + (size_t)(48 + col) * K + k0);
        acc0 = __builtin_amdgcn_mfma_f32_16x16x32_bf16(a, b0, acc0, 0, 0, 0);
        acc1 = __builtin_amdgcn_mfma_f32_16x16x32_bf16(a, b1, acc1, 0, 0, 0);
        acc2 = __builtin_amdgcn_mfma_f32_16x16x32_bf16(a, b2, acc2, 0, 0, 0);
        acc3 = __builtin_amdgcn_mfma_f32_16x16x32_bf16(a, b3, acc3, 0, 0, 0);
    }

#pragma unroll
    for (int r = 0; r < 4; r++) {
        int node = nb + quad * 4 + r;
        if (node < nn) {
            float sc = dinv[node];
            unsigned short* o = Tb + (size_t)node * 64 + col;
            o[0]  = f2bf(sc * acc0[r]);
            o[16] = f2bf(sc * acc1[r]);
            o[32] = f2bf(sc * acc2[r]);
            o[48] = f2bf(sc * acc3[r]);
        }
    }
}

// ---------------- pull aggregation, 16-deep gather pipeline ----------------
// Wave per node, lane = feature (128 B row gather per edge). 16 edges batched:
// 16 uniform ssrc loads, then 16 independent row gathers issued before any
// accumulate -> ~2 KB in flight per wave (4x the round-7 depth).
__global__ __launch_bounds__(256) void agg_kernel(const unsigned short* __restrict__ Tb,
                                                  const int* __restrict__ rowptr,
                                                  const int* __restrict__ ssrc,
                                                  const float* __restrict__ dinv,
                                                  const float* __restrict__ bias,
                                                  unsigned short* __restrict__ Ob, int nn) {
    int wave = __builtin_amdgcn_readfirstlane((blockIdx.x * 256 + threadIdx.x) >> 6);
    int lane = threadIdx.x & 63;
    if (wave >= nn) return;
    int n = wave;
    float acc = bf2f(Tb[(size_t)n * 64 + lane]);   // self loop (pre-scaled row)
    int rb = rowptr[n], re = rowptr[n + 1];
    int i = rb;
    for (; i + 16 <= re; i += 16) {
        int s[16];
#pragma unroll
        for (int k = 0; k < 16; k++) s[k] = ssrc[i + k];
        float v[16];
#pragma unroll
        for (int k = 0; k < 16; k++) v[k] = bf2f(Tb[(size_t)s[k] * 64 + lane]);
#pragma unroll
        for (int k = 0; k < 16; k++) acc += v[k];
    }
    for (; i + 4 <= re; i += 4) {
        int s0 = ssrc[i], s1 = ssrc[i + 1], s2 = ssrc[i + 2], s3 = ssrc[i + 3];
        float v0 = bf2f(Tb[(size_t)s0 * 64 + lane]);
        float v1 = bf2f(Tb[(size_t)s1 * 64 + lane]);
        float v2 = bf2f(Tb[(size_t)s2 * 64 + lane]);
        float v3 = bf2f(Tb[(size_t)s3 * 64 + lane]);
        acc += v0; acc += v1; acc += v2; acc += v3;
    }
    for (; i < re; i++)
        acc += bf2f(Tb[(size_t)ssrc[i] * 64 + lane]);
    float o = dinv[n] * acc + bias[lane];
    o = o > 0.f ? o : 0.f;
    Ob[(size_t)n * 64 + lane] = f2bf(o);
}

// ---------------- mean pool (bf16 input): exploit sorted batch ids ---------
__global__ __launch_bounds__(256) void pool_kernel(const unsigned short* __restrict__ Hb,
                                                   const int* __restrict__ batch,
                                                   float* __restrict__ pooled,
                                                   float* __restrict__ gcnt, int nn) {
    int wid = (blockIdx.x * 256 + threadIdx.x) >> 6;
    int lane = threadIdx.x & 63;
    int nwaves = (gridDim.x * 256) >> 6;
    int per = (nn + nwaves - 1) / nwaves;
    int n0 = wid * per;
    int n1 = n0 + per; if (n1 > nn) n1 = nn;
    if (n0 >= n1) return;
    int cur = batch[n0];
    float acc = 0.f, cnt = 0.f;
    for (int n = n0; n < n1; ++n) {
        int g = batch[n];
        if (g != cur) {
            atomicAdd(&pooled[cur * 64 + lane], acc);
            if (lane == 0) atomicAdd(&gcnt[cur], cnt);
            acc = 0.f; cnt = 0.f; cur = g;
        }
        acc += bf2f(Hb[(size_t)n * 64 + lane]);
        cnt += 1.f;
    }
    atomicAdd(&pooled[cur * 64 + lane], acc);
    if (lane == 0) atomicAdd(&gcnt[cur], cnt);
}

// ---------------- MLP head (single block) ----------------
__global__ __launch_bounds__(256) void head_kernel(const float* __restrict__ pooled,
                                                   const float* __restrict__ gcnt,
                                                   const float* __restrict__ Wm1,
                                                   const float* __restrict__ bm1,
                                                   const float* __restrict__ Wm2,
                                                   const float* __restrict__ bm2,
                                                   float* __restrict__ out) {
    __shared__ float P[NG * 64];
    __shared__ float Z[NG * 64];
    int tid = threadIdx.x;
    for (int i = tid; i < NG * 64; i += 256) {
        int g = i >> 6;
        float c = gcnt[g];
        c = c > 1.f ? c : 1.f;
        P[i] = pooled[i] / c;
    }
    __syncthreads();
    for (int i = tid; i < NG * 64; i += 256) {
        int g = i >> 6, j = i & 63;
        float a = bm1[j];
#pragma unroll 8
        for (int k = 0; k < 64; ++k) a += P[g * 64 + k] * Wm1[k * 64 + j];
        Z[i] = a > 0.f ? a : 0.f;
    }
    __syncthreads();
    for (int i = tid; i < NG * OUTD; i += 256) {
        int g = i / OUTD, o = i % OUTD;
        float a = bm2[o];
#pragma unroll 8
        for (int k = 0; k < 64; ++k) a += Z[g * 64 + k] * Wm2[k * OUTD + o];
        out[i] = a;
    }
}

extern "C" void kernel_launch(void* const* d_in, const int* in_sizes, int n_in,
                              void* d_out, int out_size, void* d_ws, size_t ws_size,
                              hipStream_t stream) {
    const float* x    = (const float*)d_in[0];
    const int*  edge  = (const int*)d_in[1];
    const int*  batch = (const int*)d_in[2];
    const float* W1 = (const float*)d_in[3];
    const float* b1 = (const float*)d_in[4];
    const float* W2 = (const float*)d_in[5];
    const float* b2 = (const float*)d_in[6];
    const float* W3 = (const float*)d_in[7];
    const float* b3 = (const float*)d_in[8];
    const float* Wm1 = (const float*)d_in[9];
    const float* bm1 = (const float*)d_in[10];
    const float* Wm2 = (const float*)d_in[11];
    const float* bm2 = (const float*)d_in[12];

    const int N_ = in_sizes[2];           // 100000
    const int E_ = in_sizes[1] / 2;       // 1600000
    const int* src = edge;
    const int* dst = edge + E_;
    const int nbins = (N_ + BINSZ - 1) >> BINSHIFT;   // 196

    // workspace carve (256 B aligned)
    char* w = (char*)d_ws;
    auto alloc = [&](size_t bytes) -> void* {
        void* p = (void*)w;
        w += (bytes + 255) & ~(size_t)255;
        return p;
    };
    float* dinv   = (float*)alloc((size_t)N_ * 4);
    int*   hist   = (int*)alloc((size_t)N_ * 4);
    int*   rowptr = (int*)alloc((size_t)(N_ + 1) * 4);
    int*   bsum   = (int*)alloc(512 * 4);
    int*   bbc    = (int*)alloc((size_t)256 * 256 * 4);
    int*   binTotal = (int*)alloc(256 * 4);
    int*   binStart = (int*)alloc(256 * 4);
    int*   ssrc   = (int*)alloc((size_t)E_ * 4);
    unsigned int* binned = (unsigned int*)alloc((size_t)E_ * 4);
    unsigned short* Tb  = (unsigned short*)alloc((size_t)N_ * 64 * 2);
    unsigned short* hBb = (unsigned short*)alloc((size_t)N_ * 64 * 2);
    unsigned short* WT1 = (unsigned short*)alloc((size_t)64 * IND * 2);
    unsigned short* WT2 = (unsigned short*)alloc((size_t)64 * HD * 2);
    unsigned short* WT3 = (unsigned short*)alloc((size_t)64 * HD * 2);
    float* pooled = (float*)alloc((size_t)(NG * 64 + NG) * 4);
    float* gcnt   = pooled + NG * 64;

    const int nchunks = (N_ + SCAN_CHUNK - 1) / SCAN_CHUNK;

    hipMemsetAsync(pooled, 0, (size_t)(NG * 64 + NG) * 4, stream);

    // ---- binned CSR build ----
    binA_kernel<<<PB, 256, 0, stream>>>(dst, bbc, E_, nbins);
    binB1_kernel<<<nbins, 256, 0, stream>>>(bbc, binTotal, binStart);
    scan_bsums_kernel<<<1, 64, 0, stream>>>(binStart, nbins);
    binC_kernel<<<PB, 256, 0, stream>>>(src, dst, bbc, binStart, binned, E_, nbins);
    binH_kernel<<<nbins, 256, 0, stream>>>(binned, binStart, binTotal, hist, dinv, N_);
    scan_sum_kernel<<<nchunks, 256, 0, stream>>>(hist, bsum, N_);
    scan_bsums_kernel<<<1, 64, 0, stream>>>(bsum, nchunks);
    scan_write_kernel<<<nchunks, 256, 0, stream>>>(hist, bsum, rowptr, N_, E_);
    binD_kernel<<<nbins, 256, 0, stream>>>(binned, binStart, binTotal, hist, rowptr, ssrc, N_);

    // ---- weight transposes (tiny) ----
    cvtWT_kernel<<<(64 * IND + 255) / 256, 256, 0, stream>>>(W1, WT1, IND);
    cvtWT_kernel<<<(64 * HD + 255) / 256, 256, 0, stream>>>(W2, WT2, HD);
    cvtWT_kernel<<<(64 * HD + 255) / 256, 256, 0, stream>>>(W3, WT3, HD);

    const int mmblk = (N_ + 63) / 64;             // 64 nodes per block (4 waves x 16)
    const int aggblk = (N_ + 3) / 4;              // 4 waves (nodes) per block

    // layer 1
    mm_mfma_kernel<IND, false><<<mmblk, 256, 0, stream>>>(x, WT1, dinv, Tb, N_);
    agg_kernel<<<aggblk, 256, 0, stream>>>(Tb, rowptr, ssrc, dinv, b1, hBb, N_);
    // layer 2
    mm_mfma_kernel<HD, true><<<mmblk, 256, 0, stream>>>(hBb, WT2, dinv, Tb, N_);
    agg_kernel<<<aggblk, 256, 0, stream>>>(Tb, rowptr, ssrc, dinv, b2, hBb, N_);
    // layer 3
    mm_mfma_kernel<HD, true><<<mmblk, 256, 0, stream>>>(hBb, WT3, dinv, Tb, N_);
    agg_kernel<<<aggblk, 256, 0, stream>>>(Tb, rowptr, ssrc, dinv, b3, hBb, N_);

    // pool + head
    pool_kernel<<<256, 256, 0, stream>>>(hBb, batch, pooled, gcnt, N_);
    head_kernel<<<1, 256, 0, stream>>>(pooled, gcnt, Wm1, bm1, Wm2, bm2, (float*)d_out);
}

// Round 10
// 396.459 us; speedup vs baseline: 5.3951x; 1.0367x over previous
//
#include <hip/hip_runtime.h>
#include <hip/hip_bf16.h>

#define NNODES 100000
#define NEDGES 1600000
#define IND 128
#define HD 64
#define OUTD 2
#define NG 64
#define BINSHIFT 9
#define BINSZ 512            // nodes per bin
#define PB 256               // partition blocks

typedef __attribute__((ext_vector_type(8))) short short8v;
typedef __attribute__((ext_vector_type(4))) float floatx4;

static __device__ __forceinline__ unsigned short f2bf(float f) {
    __hip_bfloat16 h = __float2bfloat16(f);
    return *(unsigned short*)&h;
}
static __device__ __forceinline__ float bf2f(unsigned short u) {
    __hip_bfloat16 h = *(__hip_bfloat16*)&u;
    return __bfloat162float(h);
}

// ============ binned CSR build ============
// A: per-block bin histogram (LDS), no global atomics.
__global__ __launch_bounds__(256) void binA_kernel(const int* __restrict__ dst,
                                                   int* __restrict__ bbc,
                                                   int E, int nbins) {
    __shared__ int lh[256];
    lh[threadIdx.x] = 0;
    __syncthreads();
    int ebpb = (E + PB - 1) / PB;
    int e0 = blockIdx.x * ebpb;
    int e1 = min(e0 + ebpb, E);
    for (int e = e0 + threadIdx.x; e < e1; e += 256)
        atomicAdd(&lh[dst[e] >> BINSHIFT], 1);
    __syncthreads();
    bbc[blockIdx.x * 256 + threadIdx.x] = lh[threadIdx.x];
}

// B1: per-bin exclusive scan across the PB partition blocks.
__global__ __launch_bounds__(256) void binB1_kernel(int* __restrict__ bbc,
                                                    int* __restrict__ binTotal,
                                                    int* __restrict__ binStart) {
    __shared__ int ws[4];
    int b = blockIdx.x;
    int t = threadIdx.x, lane = t & 63, wv = t >> 6;
    int v = bbc[t * 256 + b];
    int sc = v;
#pragma unroll
    for (int d = 1; d < 64; d <<= 1) { int u = __shfl_up(sc, d, 64); if (lane >= d) sc += u; }
    if (lane == 63) ws[wv] = sc;
    __syncthreads();
    int add = 0;
    for (int w = 0; w < wv; w++) add += ws[w];
    bbc[t * 256 + b] = sc - v + add;
    if (t == 255) { int tot = sc + add; binTotal[b] = tot; binStart[b] = tot; }
}

// 1-wave exclusive scan over nbins values in place.
__global__ __launch_bounds__(64) void scan_bsums_kernel(int* __restrict__ bsum, int nchunks) {
    int lane = threadIdx.x;
    int cpl = (nchunks + 63) / 64;     // <= 8 assumed
    int vals[8];
    int i0 = lane * cpl;
    int t = 0;
    for (int k = 0; k < cpl; k++) {
        int i = i0 + k;
        vals[k] = (i < nchunks) ? bsum[i] : 0;
        t += vals[k];
    }
    int sc = t;
#pragma unroll
    for (int d = 1; d < 64; d <<= 1) { int v = __shfl_up(sc, d, 64); if (lane >= d) sc += v; }
    int ex = sc - t;
    for (int k = 0; k < cpl; k++) {
        int i = i0 + k;
        if (i < nchunks) bsum[i] = ex;
        ex += vals[k];
    }
}

// C: partition edges into bin-contiguous packed records.
// record = (doff << 17) | src   (src < 2^17, doff < 2^9)
__global__ __launch_bounds__(256) void binC_kernel(const int* __restrict__ src,
                                                   const int* __restrict__ dst,
                                                   const int* __restrict__ bbc,
                                                   const int* __restrict__ binStart,
                                                   unsigned int* __restrict__ binned,
                                                   int E, int nbins) {
    __shared__ int cur[256];
    int t = threadIdx.x;
    if (t < nbins) cur[t] = binStart[t] + bbc[blockIdx.x * 256 + t];
    __syncthreads();
    int ebpb = (E + PB - 1) / PB;
    int e0 = blockIdx.x * ebpb;
    int e1 = min(e0 + ebpb, E);
    for (int e = e0 + t; e < e1; e += 256) {
        int d = dst[e];
        int b = d >> BINSHIFT;
        int p = atomicAdd(&cur[b], 1);
        binned[p] = ((unsigned int)(d & (BINSZ - 1)) << 17) | (unsigned int)src[e];
    }
}

// HD (merged binH + rowptr scan + binD): one block per bin.
// histogram -> dinv -> LDS exclusive scan -> rowptr (= binStart + local scan)
// -> CSR scatter with LDS countdown. No global hist, no 3-phase global scan.
__global__ __launch_bounds__(256) void binHD_kernel(const unsigned int* __restrict__ binned,
                                                    const int* __restrict__ binStart,
                                                    const int* __restrict__ binTotal,
                                                    float* __restrict__ dinv,
                                                    int* __restrict__ rowptr,
                                                    int* __restrict__ ssrc,
                                                    int n, int E) {
    __shared__ int dh[BINSZ];
    __shared__ int rp[BINSZ];
    __shared__ int wsum[4];
    int b = blockIdx.x, t = threadIdx.x;
    int lane = t & 63, wv = t >> 6;
    dh[t] = 0; dh[t + 256] = 0;
    __syncthreads();
    int s0 = binStart[b], cnt = binTotal[b];
    for (int i = t; i < cnt; i += 256)
        atomicAdd(&dh[binned[s0 + i] >> 17], 1);
    __syncthreads();
    // dinv (deg + self loop)
#pragma unroll
    for (int r = 0; r < 2; r++) {
        int i = t + r * 256;
        int node = (b << BINSHIFT) + i;
        if (node < n) dinv[node] = 1.0f / sqrtf((float)(dh[i] + 1));
    }
    // exclusive scan of dh[0..511]; thread t owns elements 2t, 2t+1
    int d0 = dh[2 * t], d1 = dh[2 * t + 1];
    int p = d0 + d1;
    int sc = p;
#pragma unroll
    for (int d = 1; d < 64; d <<= 1) { int v = __shfl_up(sc, d, 64); if (lane >= d) sc += v; }
    if (lane == 63) wsum[wv] = sc;
    __syncthreads();
    int add = 0;
    for (int w2 = 0; w2 < wv; w2++) add += wsum[w2];
    int ex = sc - p + add;
    rp[2 * t]     = ex;
    rp[2 * t + 1] = ex + d0;
    __syncthreads();
    // global CSR rowptr
#pragma unroll
    for (int r = 0; r < 2; r++) {
        int i = t + r * 256;
        int node = (b << BINSHIFT) + i;
        if (node < n) rowptr[node] = s0 + rp[i];
    }
    if (b == 0 && t == 0) rowptr[n] = E;
    __syncthreads();
    // scatter (dh consumed as countdown)
    for (int i = t; i < cnt; i += 256) {
        unsigned int rec = binned[s0 + i];
        int doff = rec >> 17;
        int s = rec & 0x1FFFF;
        int idx = atomicSub(&dh[doff], 1) - 1;
        ssrc[s0 + rp[doff] + idx] = s;
    }
}

// ---------------- all 3 W transposes in one dispatch ----------------
__global__ __launch_bounds__(256) void cvtWT3_kernel(const float* __restrict__ W1,
                                                     const float* __restrict__ W2,
                                                     const float* __restrict__ W3,
                                                     unsigned short* __restrict__ WT1,
                                                     unsigned short* __restrict__ WT2,
                                                     unsigned short* __restrict__ WT3) {
    int i = blockIdx.x * 256 + threadIdx.x;
    if (i < 64 * IND) {
        int n = i / IND, k = i - n * IND;
        WT1[i] = f2bf(W1[k * 64 + n]);
    } else if (i < 64 * IND + 64 * HD) {
        int j = i - 64 * IND;
        int n = j / HD, k = j - n * HD;
        WT2[j] = f2bf(W2[k * 64 + n]);
    } else if (i < 64 * IND + 2 * 64 * HD) {
        int j = i - 64 * IND - 64 * HD;
        int n = j / HD, k = j - n * HD;
        WT3[j] = f2bf(W3[k * 64 + n]);
    }
}

// ---------------- MFMA matmul: Tb[n][:] = bf16( dinv[n] * (X[n,:K] @ W) ) --
template <int K, bool BF16IN>
__global__ __launch_bounds__(256) void mm_mfma_kernel(const void* __restrict__ Xv,
                                                      const unsigned short* __restrict__ WT,
                                                      const float* __restrict__ dinv,
                                                      unsigned short* __restrict__ Tb, int nn) {
    const int lane = threadIdx.x & 63;
    const int wv   = threadIdx.x >> 6;
    const int nb   = blockIdx.x * 64 + wv * 16;
    if (nb >= nn) return;
    const int col  = lane & 15;
    const int quad = lane >> 4;
    const int m    = min(nb + col, nn - 1);

    floatx4 acc0 = {0.f, 0.f, 0.f, 0.f};
    floatx4 acc1 = {0.f, 0.f, 0.f, 0.f};
    floatx4 acc2 = {0.f, 0.f, 0.f, 0.f};
    floatx4 acc3 = {0.f, 0.f, 0.f, 0.f};

#pragma unroll
    for (int ks = 0; ks < K; ks += 32) {
        const int k0 = ks + quad * 8;
        short8v a;
        if (BF16IN) {
            a = *(const short8v*)((const unsigned short*)Xv + (size_t)m * K + k0);
        } else {
            const float* xr = (const float*)Xv + (size_t)m * K + k0;
            float4 f0 = *(const float4*)(xr);
            float4 f1 = *(const float4*)(xr + 4);
            a[0] = (short)f2bf(f0.x); a[1] = (short)f2bf(f0.y);
            a[2] = (short)f2bf(f0.z); a[3] = (short)f2bf(f0.w);
            a[4] = (short)f2bf(f1.x); a[5] = (short)f2bf(f1.y);
            a[6] = (short)f2bf(f1.z); a[7] = (short)f2bf(f1.w);
        }
        short8v b0 = *(const short8v*)(WT + (size_t)(0  + col) * K + k0);
        short8v b1 = *(const short8v*)(WT + (size_t)(16 + col) * K + k0);
        short8v b2 = *(const short8v*)(WT + (size_t)(32 + col) * K + k0);
        short8v b3 = *(const short8v*)(WT + (size_t)(48 + col) * K + k0);
        acc0 = __builtin_amdgcn_mfma_f32_16x16x32_bf16(a, b0, acc0, 0, 0, 0);
        acc1 = __builtin_amdgcn_mfma_f32_16x16x32_bf16(a, b1, acc1, 0, 0, 0);
        acc2 = __builtin_amdgcn_mfma_f32_16x16x32_bf16(a, b2, acc2, 0, 0, 0);
        acc3 = __builtin_amdgcn_mfma_f32_16x16x32_bf16(a, b3, acc3, 0, 0, 0);
    }

#pragma unroll
    for (int r = 0; r < 4; r++) {
        int node = nb + quad * 4 + r;
        if (node < nn) {
            float sc = dinv[node];
            unsigned short* o = Tb + (size_t)node * 64 + col;
            o[0]  = f2bf(sc * acc0[r]);
            o[16] = f2bf(sc * acc1[r]);
            o[32] = f2bf(sc * acc2[r]);
            o[48] = f2bf(sc * acc3[r]);
        }
    }
}

// ---------------- pull aggregation, 16-deep gather pipeline ----------------
__global__ __launch_bounds__(256) void agg_kernel(const unsigned short* __restrict__ Tb,
                                                  const int* __restrict__ rowptr,
                                                  const int* __restrict__ ssrc,
                                                  const float* __restrict__ dinv,
                                                  const float* __restrict__ bias,
                                                  unsigned short* __restrict__ Ob, int nn) {
    int wave = __builtin_amdgcn_readfirstlane((blockIdx.x * 256 + threadIdx.x) >> 6);
    int lane = threadIdx.x & 63;
    if (wave >= nn) return;
    int n = wave;
    float acc = bf2f(Tb[(size_t)n * 64 + lane]);   // self loop (pre-scaled row)
    int rb = rowptr[n], re = rowptr[n + 1];
    int i = rb;
    for (; i + 16 <= re; i += 16) {
        int s[16];
#pragma unroll
        for (int k = 0; k < 16; k++) s[k] = ssrc[i + k];
        float v[16];
#pragma unroll
        for (int k = 0; k < 16; k++) v[k] = bf2f(Tb[(size_t)s[k] * 64 + lane]);
#pragma unroll
        for (int k = 0; k < 16; k++) acc += v[k];
    }
    for (; i + 4 <= re; i += 4) {
        int s0 = ssrc[i], s1 = ssrc[i + 1], s2 = ssrc[i + 2], s3 = ssrc[i + 3];
        float v0 = bf2f(Tb[(size_t)s0 * 64 + lane]);
        float v1 = bf2f(Tb[(size_t)s1 * 64 + lane]);
        float v2 = bf2f(Tb[(size_t)s2 * 64 + lane]);
        float v3 = bf2f(Tb[(size_t)s3 * 64 + lane]);
        acc += v0; acc += v1; acc += v2; acc += v3;
    }
    for (; i < re; i++)
        acc += bf2f(Tb[(size_t)ssrc[i] * 64 + lane]);
    float o = dinv[n] * acc + bias[lane];
    o = o > 0.f ? o : 0.f;
    Ob[(size_t)n * 64 + lane] = f2bf(o);
}

// ---------------- mean pool (bf16 input): exploit sorted batch ids ---------
__global__ __launch_bounds__(256) void pool_kernel(const unsigned short* __restrict__ Hb,
                                                   const int* __restrict__ batch,
                                                   float* __restrict__ pooled,
                                                   float* __restrict__ gcnt, int nn) {
    int wid = (blockIdx.x * 256 + threadIdx.x) >> 6;
    int lane = threadIdx.x & 63;
    int nwaves = (gridDim.x * 256) >> 6;
    int per = (nn + nwaves - 1) / nwaves;
    int n0 = wid * per;
    int n1 = n0 + per; if (n1 > nn) n1 = nn;
    if (n0 >= n1) return;
    int cur = batch[n0];
    float acc = 0.f, cnt = 0.f;
    for (int n = n0; n < n1; ++n) {
        int g = batch[n];
        if (g != cur) {
            atomicAdd(&pooled[cur * 64 + lane], acc);
            if (lane == 0) atomicAdd(&gcnt[cur], cnt);
            acc = 0.f; cnt = 0.f; cur = g;
        }
        acc += bf2f(Hb[(size_t)n * 64 + lane]);
        cnt += 1.f;
    }
    atomicAdd(&pooled[cur * 64 + lane], acc);
    if (lane == 0) atomicAdd(&gcnt[cur], cnt);
}

// ---------------- MLP head (single block) ----------------
__global__ __launch_bounds__(256) void head_kernel(const float* __restrict__ pooled,
                                                   const float* __restrict__ gcnt,
                                                   const float* __restrict__ Wm1,
                                                   const float* __restrict__ bm1,
                                                   const float* __restrict__ Wm2,
                                                   const float* __restrict__ bm2,
                                                   float* __restrict__ out) {
    __shared__ float P[NG * 64];
    __shared__ float Z[NG * 64];
    int tid = threadIdx.x;
    for (int i = tid; i < NG * 64; i += 256) {
        int g = i >> 6;
        float c = gcnt[g];
        c = c > 1.f ? c : 1.f;
        P[i] = pooled[i] / c;
    }
    __syncthreads();
    for (int i = tid; i < NG * 64; i += 256) {
        int g = i >> 6, j = i & 63;
        float a = bm1[j];
#pragma unroll 8
        for (int k = 0; k < 64; ++k) a += P[g * 64 + k] * Wm1[k * 64 + j];
        Z[i] = a > 0.f ? a : 0.f;
    }
    __syncthreads();
    for (int i = tid; i < NG * OUTD; i += 256) {
        int g = i / OUTD, o = i % OUTD;
        float a = bm2[o];
#pragma unroll 8
        for (int k = 0; k < 64; ++k) a += Z[g * 64 + k] * Wm2[k * OUTD + o];
        out[i] = a;
    }
}

extern "C" void kernel_launch(void* const* d_in, const int* in_sizes, int n_in,
                              void* d_out, int out_size, void* d_ws, size_t ws_size,
                              hipStream_t stream) {
    const float* x    = (const float*)d_in[0];
    const int*  edge  = (const int*)d_in[1];
    const int*  batch = (const int*)d_in[2];
    const float* W1 = (const float*)d_in[3];
    const float* b1 = (const float*)d_in[4];
    const float* W2 = (const float*)d_in[5];
    const float* b2 = (const float*)d_in[6];
    const float* W3 = (const float*)d_in[7];
    const float* b3 = (const float*)d_in[8];
    const float* Wm1 = (const float*)d_in[9];
    const float* bm1 = (const float*)d_in[10];
    const float* Wm2 = (const float*)d_in[11];
    const float* bm2 = (const float*)d_in[12];

    const int N_ = in_sizes[2];           // 100000
    const int E_ = in_sizes[1] / 2;       // 1600000
    const int* src = edge;
    const int* dst = edge + E_;
    const int nbins = (N_ + BINSZ - 1) >> BINSHIFT;   // 196

    // workspace carve (256 B aligned)
    char* w = (char*)d_ws;
    auto alloc = [&](size_t bytes) -> void* {
        void* p = (void*)w;
        w += (bytes + 255) & ~(size_t)255;
        return p;
    };
    float* dinv   = (float*)alloc((size_t)N_ * 4);
    int*   rowptr = (int*)alloc((size_t)(N_ + 1) * 4);
    int*   bbc    = (int*)alloc((size_t)256 * 256 * 4);
    int*   binTotal = (int*)alloc(256 * 4);
    int*   binStart = (int*)alloc(256 * 4);
    int*   ssrc   = (int*)alloc((size_t)E_ * 4);
    unsigned int* binned = (unsigned int*)alloc((size_t)E_ * 4);
    unsigned short* Tb  = (unsigned short*)alloc((size_t)N_ * 64 * 2);
    unsigned short* hBb = (unsigned short*)alloc((size_t)N_ * 64 * 2);
    unsigned short* WT1 = (unsigned short*)alloc((size_t)64 * IND * 2);
    unsigned short* WT2 = (unsigned short*)alloc((size_t)64 * HD * 2);
    unsigned short* WT3 = (unsigned short*)alloc((size_t)64 * HD * 2);
    float* pooled = (float*)alloc((size_t)(NG * 64 + NG) * 4);
    float* gcnt   = pooled + NG * 64;

    hipMemsetAsync(pooled, 0, (size_t)(NG * 64 + NG) * 4, stream);

    // ---- binned CSR build (5 dispatches) ----
    binA_kernel<<<PB, 256, 0, stream>>>(dst, bbc, E_, nbins);
    binB1_kernel<<<nbins, 256, 0, stream>>>(bbc, binTotal, binStart);
    scan_bsums_kernel<<<1, 64, 0, stream>>>(binStart, nbins);
    binC_kernel<<<PB, 256, 0, stream>>>(src, dst, bbc, binStart, binned, E_, nbins);
    binHD_kernel<<<nbins, 256, 0, stream>>>(binned, binStart, binTotal, dinv, rowptr, ssrc, N_, E_);

    // ---- weight transposes (1 dispatch) ----
    cvtWT3_kernel<<<(64 * IND + 2 * 64 * HD + 255) / 256, 256, 0, stream>>>(
        W1, W2, W3, WT1, WT2, WT3);

    const int mmblk = (N_ + 63) / 64;             // 64 nodes per block (4 waves x 16)
    const int aggblk = (N_ + 3) / 4;              // 4 waves (nodes) per block

    // layer 1
    mm_mfma_kernel<IND, false><<<mmblk, 256, 0, stream>>>(x, WT1, dinv, Tb, N_);
    agg_kernel<<<aggblk, 256, 0, stream>>>(Tb, rowptr, ssrc, dinv, b1, hBb, N_);
    // layer 2
    mm_mfma_kernel<HD, true><<<mmblk, 256, 0, stream>>>(hBb, WT2, dinv, Tb, N_);
    agg_kernel<<<aggblk, 256, 0, stream>>>(Tb, rowptr, ssrc, dinv, b2, hBb, N_);
    // layer 3
    mm_mfma_kernel<HD, true><<<mmblk, 256, 0, stream>>>(hBb, WT3, dinv, Tb, N_);
    agg_kernel<<<aggblk, 256, 0, stream>>>(Tb, rowptr, ssrc, dinv, b3, hBb, N_);

    // pool + head
    pool_kernel<<<256, 256, 0, stream>>>(hBb, batch, pooled, gcnt, N_);
    head_kernel<<<1, 256, 0, stream>>>(pooled, gcnt, Wm1, bm1, Wm2, bm2, (float*)d_out);
}